// Round 1
// 223.432 us; speedup vs baseline: 1.0420x; 1.0420x over previous
//
#include <hip/hip_runtime.h>

// ---------------------------------------------------------------------------
// SAGEEncoder: 2-layer GraphSAGE, N=100000, d=128, E=1.6M.
// Pipeline: x->bf16 | weights->bf16 swizzled (once) | bucket-bin edges by
// dst>>7 (LDS-staged) | per-bucket counting-sort -> node-sorted CSR |
// wave-per-node gather (dwordx4: 4 rows / 1KB per instruction) | fused
// dual-GEMM.
// ---------------------------------------------------------------------------

using bf16x8 = __attribute__((ext_vector_type(8))) __bf16;
using f32x4  = __attribute__((ext_vector_type(4))) float;

__device__ __forceinline__ unsigned short f2bf(float f) {
    __bf16 b = (__bf16)f;                       // RNE
    return __builtin_bit_cast(unsigned short, b);
}
__device__ __forceinline__ unsigned pk2(float a, float b) {
    return (unsigned)f2bf(a) | ((unsigned)f2bf(b) << 16);
}
__device__ __forceinline__ float bf2f(unsigned u16) {
    unsigned v = u16 << 16;
    return __builtin_bit_cast(float, v);
}

// exclusive scan over 1024 threads (16 waves), ~2 barriers
__device__ __forceinline__ int exscan1024(int v, int* wsum, int t) {
    int lane = t & 63, w = t >> 6;
    int x = v;
#pragma unroll
    for (int s = 1; s < 64; s <<= 1) {
        int y = __shfl_up(x, s);
        if (lane >= s) x += y;
    }
    if (lane == 63) wsum[w] = x;
    __syncthreads();
    if (w == 0) {
        int ws = (lane < 16) ? wsum[lane] : 0;
#pragma unroll
        for (int s = 1; s < 16; s <<= 1) {
            int y = __shfl_up(ws, s);
            if (lane >= s) ws += y;
        }
        if (lane < 16) wsum[lane] = ws;          // inclusive wave sums
    }
    __syncthreads();
    int base = (w > 0) ? wsum[w - 1] : 0;
    return base + x - v;
}

// ---------------- x fp32 -> bf16, + zero bucket histogram -------------------

__global__ __launch_bounds__(256) void k_cvt(const float4* __restrict__ x,
                                             uint4* __restrict__ xb8,
                                             int nvec, int* __restrict__ ghist, int nb)
{
    int i = blockIdx.x * 256 + threadIdx.x;
    if (i < nb) ghist[i] = 0;
    if (i >= nvec) return;
    float4 a = x[2 * i], b = x[2 * i + 1];
    uint4 o;
    o.x = pk2(a.x, a.y);
    o.y = pk2(a.z, a.w);
    o.z = pk2(b.x, b.y);
    o.w = pk2(b.z, b.w);
    xb8[i] = o;
}

// ---------------- weights fp32 -> bf16 swizzled (once) ----------------------
// wsw[m][c*128 + (k ^ ((c&7)<<3))] = bf16(W[m][k*128+c]),  m in 0..3

__global__ __launch_bounds__(256) void k_cvtw(const float* __restrict__ W0,
                                              const float* __restrict__ W1,
                                              const float* __restrict__ W2,
                                              const float* __restrict__ W3,
                                              unsigned short* __restrict__ wsw)
{
    int id = blockIdx.x * 256 + threadIdx.x;     // 65536 total
    int m = id >> 14, r = id & 16383;
    int c = r >> 7, k = r & 127;
    const float* W = (m == 0) ? W0 : (m == 1) ? W1 : (m == 2) ? W2 : W3;
    wsw[m * 16384 + c * 128 + (k ^ ((c & 7) << 3))] = f2bf(W[k * 128 + c]);
}

// ---------------- bucket histogram (dst >> 7) -------------------------------

__global__ __launch_bounds__(256) void k_binhist(const int* __restrict__ dst, int E,
                                                 int* __restrict__ ghist, int nb)
{
    __shared__ int lh[800];
    for (int i = threadIdx.x; i < nb; i += 256) lh[i] = 0;
    __syncthreads();
    for (int e = blockIdx.x * 256 + threadIdx.x; e < E; e += gridDim.x * 256)
        atomicAdd(&lh[dst[e] >> 7], 1);
    __syncthreads();
    for (int i = threadIdx.x; i < nb; i += 256)
        if (lh[i]) atomicAdd(&ghist[i], lh[i]);
}

// ---------------- bucket base scan ------------------------------------------

__global__ __launch_bounds__(1024) void k_binscan(const int* __restrict__ ghist,
                                                  int* __restrict__ gbase,
                                                  int* __restrict__ gcur,
                                                  int* __restrict__ row_start,
                                                  int nb, int n, int E)
{
    __shared__ int wsum[16];
    int t = threadIdx.x;
    int v = (t < nb) ? ghist[t] : 0;
    int excl = exscan1024(v, wsum, t);
    if (t < nb) { gbase[t] = excl; gcur[t] = excl; }
    if (t == 0) { gbase[nb] = E; row_start[n] = E; }
}

// ---------------- binned scatter (LDS-staged, sorted writes) ----------------
// packed word: (src << 7) | (dst & 127)

#define SC_CHUNK 8192

__global__ __launch_bounds__(1024) void k_binscatter(const int* __restrict__ src,
                                                     const int* __restrict__ dst, int E,
                                                     int* __restrict__ gcur,
                                                     unsigned* __restrict__ binned, int nb)
{
    __shared__ int lh[800];        // hist, then running cursor
    __shared__ int lbase[800];
    __shared__ int gb[800];
    __shared__ int wsum[16];
    __shared__ unsigned long long staged[SC_CHUNK];   // 64 KiB
    int t = threadIdx.x;
    int e0 = blockIdx.x * SC_CHUNK;
    if (e0 >= E) return;
    int ecnt = E - e0; if (ecnt > SC_CHUNK) ecnt = SC_CHUNK;

    for (int i = t; i < nb; i += 1024) lh[i] = 0;
    __syncthreads();
    for (int i = t; i < ecnt; i += 1024)
        atomicAdd(&lh[dst[e0 + i] >> 7], 1);
    __syncthreads();
    int v = (t < nb) ? lh[t] : 0;
    int excl = exscan1024(v, wsum, t);
    if (t < nb) {
        lbase[t] = excl;
        gb[t] = v ? atomicAdd(&gcur[t], v) : 0;
        lh[t] = excl;                       // running cursor
    }
    __syncthreads();
    for (int i = t; i < ecnt; i += 1024) {
        int d = dst[e0 + i], s = src[e0 + i];
        int b = d >> 7;
        int rank = atomicAdd(&lh[b], 1);
        unsigned pack = ((unsigned)s << 7) | (unsigned)(d & 127);
        unsigned gaddr = (unsigned)gb[b] + (unsigned)(rank - lbase[b]);
        staged[rank] = ((unsigned long long)gaddr << 32) | pack;
    }
    __syncthreads();
    for (int i = t; i < ecnt; i += 1024) {
        unsigned long long w = staged[i];
        binned[(unsigned)(w >> 32)] = (unsigned)w;
    }
}

// ---------------- per-bucket counting sort -> node-sorted CSR ---------------

#define BS_STAGE 8192

__global__ __launch_bounds__(256) void k_bucketsort(
    const unsigned* __restrict__ binned,
    const int* __restrict__ gbase,
    int* __restrict__ csr,
    int* __restrict__ row_start,
    float* __restrict__ inv_deg,
    int n)
{
    __shared__ int cnt[128];
    __shared__ int cur[128];
    __shared__ int wsum[4];
    __shared__ unsigned stg[BS_STAGE];     // 32 KiB
    const int t = threadIdx.x;
    const int b = blockIdx.x;
    const int beg = gbase[b], end = gbase[b + 1];
    const int len = end - beg;

    if (t < 128) cnt[t] = 0;
    __syncthreads();
    for (int i = beg + t; i < end; i += 256)
        atomicAdd(&cnt[binned[i] & 127], 1);
    __syncthreads();
    // exclusive scan over 128 counts (2 waves, shfl)
    int v = (t < 128) ? cnt[t] : 0;
    {
        int lane = t & 63, w = t >> 6;
        int x = v;
#pragma unroll
        for (int s = 1; s < 64; s <<= 1) {
            int y = __shfl_up(x, s);
            if (lane >= s) x += y;
        }
        if (lane == 63) wsum[w] = x;
        __syncthreads();
        int base = (w == 1) ? wsum[0] : (w == 2) ? wsum[0] + wsum[1]
                 : (w == 3) ? wsum[0] + wsum[1] + wsum[2] : 0;
        int excl = base + x - v;
        if (t < 128) {
            cur[t] = excl;
            int node = b * 128 + t;
            if (node < n) {
                row_start[node] = beg + excl;
                inv_deg[node] = 1.f / (float)max(v, 1);
            }
        }
    }
    __syncthreads();

    if (len <= BS_STAGE) {
        for (int i = beg + t; i < end; i += 256) {
            unsigned w = binned[i];
            int r = atomicAdd(&cur[w & 127], 1);
            stg[r] = w >> 7;
        }
        __syncthreads();
        for (int i = t; i < len; i += 256)
            csr[beg + i] = (int)stg[i];
    } else {   // overflow fallback (unreachable for this input)
        for (int i = beg + t; i < end; i += 256) {
            unsigned w = binned[i];
            int r = atomicAdd(&cur[w & 127], 1);
            csr[beg + r] = (int)(w >> 7);
        }
    }
}

// ---------------- mean aggregation: one wave per node -----------------------
// dwordx4 gather: 4 neighbor rows per load instruction (quarter-wave q picks
// the row, lane&15 picks the 16B column slice). 4 loads (4 KB) in flight per
// wave. Quarter-partials reduced with 2x shfl_xor at the end.

__device__ __forceinline__ void acc8(float* a, uint4 v) {
    a[0] += __builtin_bit_cast(float, v.x << 16);
    a[1] += __builtin_bit_cast(float, v.x & 0xffff0000u);
    a[2] += __builtin_bit_cast(float, v.y << 16);
    a[3] += __builtin_bit_cast(float, v.y & 0xffff0000u);
    a[4] += __builtin_bit_cast(float, v.z << 16);
    a[5] += __builtin_bit_cast(float, v.z & 0xffff0000u);
    a[6] += __builtin_bit_cast(float, v.w << 16);
    a[7] += __builtin_bit_cast(float, v.w & 0xffff0000u);
}

__global__ __launch_bounds__(256) void k_agg(
    const unsigned short* __restrict__ feat,
    const int* __restrict__ csr,
    const int* __restrict__ row_start,
    const float* __restrict__ inv_deg,
    unsigned short* __restrict__ mean, int n)
{
    int node = blockIdx.x * 4 + (threadIdx.x >> 6);
    if (node >= n) return;
    const int lane = threadIdx.x & 63;
    const int q  = lane >> 4;            // quarter: which of 4 rows per load
    const int cg = (lane & 15) << 3;     // column base (8 bf16 = 16 B / lane)
    const int beg = row_start[node], end = row_start[node + 1];

    float a[8];
#pragma unroll
    for (int j = 0; j < 8; ++j) a[j] = 0.f;

    for (int i = beg; i < end; i += 64) {
        int cnt = end - i; if (cnt > 64) cnt = 64;
        int idx = csr[i + (lane < cnt ? lane : cnt - 1)];
        for (int e = 0; e < cnt; e += 16) {
            const int r0 = e + q, r1 = e + 4 + q, r2 = e + 8 + q, r3 = e + 12 + q;
            int s0 = __shfl(idx, r0 < cnt ? r0 : cnt - 1);
            int s1 = __shfl(idx, r1 < cnt ? r1 : cnt - 1);
            int s2 = __shfl(idx, r2 < cnt ? r2 : cnt - 1);
            int s3 = __shfl(idx, r3 < cnt ? r3 : cnt - 1);
            uint4 v0 = *(const uint4*)(feat + ((size_t)s0 << 7) + cg);
            uint4 v1 = *(const uint4*)(feat + ((size_t)s1 << 7) + cg);
            uint4 v2 = *(const uint4*)(feat + ((size_t)s2 << 7) + cg);
            uint4 v3 = *(const uint4*)(feat + ((size_t)s3 << 7) + cg);
            if (r0 < cnt) acc8(a, v0);
            if (r1 < cnt) acc8(a, v1);
            if (r2 < cnt) acc8(a, v2);
            if (r3 < cnt) acc8(a, v3);
        }
    }

    // sum the 4 quarter-partials (rows taken mod 4) per column group
#pragma unroll
    for (int j = 0; j < 8; ++j) {
        a[j] += __shfl_xor(a[j], 16);
        a[j] += __shfl_xor(a[j], 32);
    }

    if (q == 0) {
        float w = inv_deg[node];
        uint4 o;
        o.x = pk2(a[0] * w, a[1] * w);
        o.y = pk2(a[2] * w, a[3] * w);
        o.z = pk2(a[4] * w, a[5] * w);
        o.w = pk2(a[6] * w, a[7] * w);
        *(uint4*)(mean + (size_t)node * 128 + cg) = o;
    }
}

// ----------------------------- fused GEMM ----------------------------------
// out[r][c] = act( sum_k A1[r][k]*W1[k][c] + A2[r][k]*W2[k][c] + bias[c] )
// Wsw: pre-swizzled bf16 weight pair (W1 at 0, W2 at 16384).
// out may alias A2: __syncthreads() before epilogue; each block reads only
// its own 128 rows.

template<bool RELU, bool OUTF32>
__global__ __launch_bounds__(256) void k_gemm(
    const unsigned short* __restrict__ A1,
    const unsigned short* __restrict__ A2,
    const unsigned short* __restrict__ Wsw,
    const float* __restrict__ bias,
    void* __restrict__ outv,
    int nrows)
{
    __shared__ __align__(16) unsigned short Wt[2 * 128 * 128];  // 64 KiB
    {
        const uint4* wsrc = (const uint4*)Wsw;
        uint4* wdst = (uint4*)Wt;
#pragma unroll
        for (int i = 0; i < 16; ++i)
            wdst[threadIdx.x + 256 * i] = wsrc[threadIdx.x + 256 * i];
    }
    __syncthreads();

    const int lane = threadIdx.x & 63;
    const int wave = threadIdx.x >> 6;
    const int lr = lane & 15;
    const int lg = lane >> 4;
    const int row0 = blockIdx.x * 128 + wave * 32;
    const int sw = (lr & 7) << 3;

    f32x4 acc[2][8];
#pragma unroll
    for (int m = 0; m < 2; ++m)
#pragma unroll
        for (int nn = 0; nn < 8; ++nn) acc[m][nn] = (f32x4){0.f, 0.f, 0.f, 0.f};

#pragma unroll
    for (int ks = 0; ks < 4; ++ks) {
        const int k0 = ks * 32 + lg * 8;
        bf16x8 a1[2], a2[2];
#pragma unroll
        for (int m = 0; m < 2; ++m) {
            int r = row0 + m * 16 + lr;
            if (r >= nrows) r = nrows - 1;           // clamp (stores masked)
            a1[m] = *reinterpret_cast<const bf16x8*>(A1 + (size_t)r * 128 + k0);
            a2[m] = *reinterpret_cast<const bf16x8*>(A2 + (size_t)r * 128 + k0);
        }
        const int kidx = k0 ^ sw;
#pragma unroll
        for (int nn = 0; nn < 8; ++nn) {
            const int c = nn * 16 + lr;
            bf16x8 b1 = *reinterpret_cast<const bf16x8*>(&Wt[c * 128 + kidx]);
            bf16x8 b2 = *reinterpret_cast<const bf16x8*>(&Wt[16384 + c * 128 + kidx]);
#pragma unroll
            for (int m = 0; m < 2; ++m) {
                acc[m][nn] = __builtin_amdgcn_mfma_f32_16x16x32_bf16(a1[m], b1, acc[m][nn], 0, 0, 0);
                acc[m][nn] = __builtin_amdgcn_mfma_f32_16x16x32_bf16(a2[m], b2, acc[m][nn], 0, 0, 0);
            }
        }
    }

    __syncthreads();   // all A reads done block-wide (out may alias A2)

#pragma unroll
    for (int m = 0; m < 2; ++m) {
#pragma unroll
        for (int nn = 0; nn < 8; ++nn) {
            const int c = nn * 16 + lr;
            const float bv = bias[c];
#pragma unroll
            for (int i = 0; i < 4; ++i) {
                int r = row0 + m * 16 + lg * 4 + i;
                if (r < nrows) {
                    float v = acc[m][nn][i] + bv;
                    if (RELU) v = fmaxf(v, 0.f);
                    if (OUTF32)
                        ((float*)outv)[(size_t)r * 128 + c] = v;
                    else
                        ((unsigned short*)outv)[(size_t)r * 128 + c] = f2bf(v);
                }
            }
        }
    }
}

// ----------------------------- launcher ------------------------------------

extern "C" void kernel_launch(void* const* d_in, const int* in_sizes, int n_in,
                              void* d_out, int out_size, void* d_ws, size_t ws_size,
                              hipStream_t stream)
{
    const float* x   = (const float*)d_in[0];
    const int*   ei  = (const int*)d_in[1];
    const float* Wl0 = (const float*)d_in[2];
    const float* Wr0 = (const float*)d_in[3];
    const float* b0  = (const float*)d_in[4];
    const float* Wl1 = (const float*)d_in[5];
    const float* Wr1 = (const float*)d_in[6];
    const float* b1  = (const float*)d_in[7];
    float* out = (float*)d_out;

    const int n = in_sizes[0] / 128;      // 100000
    const int E = in_sizes[1] / 2;        // 1600000
    const int* src = ei;
    const int* dst = ei + E;
    const int nb = (n + 127) >> 7;        // 782 buckets

    char* ws = (char*)d_ws;
    size_t off = 0;
    auto alloc = [&](size_t sz) -> char* {
        char* p = ws + off;
        off += (sz + 1023) & ~(size_t)1023;
        return p;
    };
    unsigned short* xb     = (unsigned short*)alloc((size_t)n * 128 * 2);  // also h (aliased)
    unsigned short* mean   = (unsigned short*)alloc((size_t)n * 128 * 2);
    unsigned*       binned = (unsigned*)      alloc((size_t)E * 4);
    int*            rs     = (int*)           alloc((size_t)(n + 1) * 4);
    float*          invd   = (float*)         alloc((size_t)n * 4);
    int*            ghist  = (int*)           alloc((size_t)nb * 4);
    int*            gbase  = (int*)           alloc((size_t)(nb + 1) * 4);
    int*            gcur   = (int*)           alloc((size_t)nb * 4);
    unsigned short* wsw    = (unsigned short*)alloc(4 * 16384 * 2);
    int* csr;
    if (off + (size_t)E * 4 <= ws_size) csr = (int*)alloc((size_t)E * 4);
    else                                csr = (int*)binned;
    if (ws_size < off) return;

    const int nvec = n * 128 / 8;         // 1.6M
    const int nsc  = (E + SC_CHUNK - 1) / SC_CHUNK;

    hipLaunchKernelGGL(k_cvt,        dim3((nvec + 255) / 256), dim3(256),  0, stream,
                       (const float4*)x, (uint4*)xb, nvec, ghist, nb);
    hipLaunchKernelGGL(k_cvtw,       dim3(256),                dim3(256),  0, stream,
                       Wl0, Wr0, Wl1, Wr1, wsw);
    hipLaunchKernelGGL(k_binhist,    dim3(512),                dim3(256),  0, stream,
                       dst, E, ghist, nb);
    hipLaunchKernelGGL(k_binscan,    dim3(1),                  dim3(1024), 0, stream,
                       ghist, gbase, gcur, rs, nb, n, E);
    hipLaunchKernelGGL(k_binscatter, dim3(nsc),                dim3(1024), 0, stream,
                       src, dst, E, gcur, binned, nb);
    hipLaunchKernelGGL(k_bucketsort, dim3(nb),                 dim3(256),  0, stream,
                       binned, gbase, csr, rs, invd, n);
    // layer 0
    hipLaunchKernelGGL(k_agg,  dim3((n + 3) / 4), dim3(256), 0, stream,
                       xb, csr, rs, invd, mean, n);
    hipLaunchKernelGGL((k_gemm<true, false>), dim3(nb), dim3(256), 0, stream,
                       mean, xb, wsw, b0, (void*)xb, n);          // h aliases xb
    // layer 1
    hipLaunchKernelGGL(k_agg,  dim3((n + 3) / 4), dim3(256), 0, stream,
                       xb, csr, rs, invd, mean, n);
    hipLaunchKernelGGL((k_gemm<false, true>), dim3(nb), dim3(256), 0, stream,
                       mean, xb, wsw + 2 * 16384, b1, (void*)out, n);
}